// Round 2
// baseline (135.352 us; speedup 1.0000x reference)
//
#include <hip/hip_runtime.h>

// Segmented Gumbel-argmax sampler.
// out[g] = within-group rank (int32) of argmax_{i: index[i]==g} (logits[i]+z[i]),
//          first occurrence wins ties (min item idx at max y).
//
// N_ITEMS = 8388608, N_GROUPS = 512.  Output dtype: int32 (written as int).

#define G           512
#define NBLK        512        // pass1 blocks; each owns a contiguous chunk
#define BLK         256
#define CHUNK_ITEMS 16384      // N_ITEMS / NBLK
#define CHUNK_VEC   4096       // CHUNK_ITEMS / 4 (float4 / int4 per chunk)

// monotone order-preserving float32 -> uint32 map (no NaNs in input)
__device__ __forceinline__ unsigned int ord_f32(float f) {
    unsigned int u = __float_as_uint(f);
    return (u & 0x80000000u) ? ~u : (u | 0x80000000u);
}

// -----------------------------------------------------------------------------
// pass1: per-chunk segmented max-key + per-chunk group counts.
// ws_key[g*NBLK + b] = max key of group g within chunk b (0 if absent)
// ws_cnt[g*NBLK + b] = #items of group g within chunk b
// -----------------------------------------------------------------------------
__global__ __launch_bounds__(BLK) void pass1(const float4* __restrict__ lg,
                                             const float4* __restrict__ zz,
                                             const int4*   __restrict__ ix,
                                             unsigned long long* __restrict__ ws_key,
                                             unsigned int*       __restrict__ ws_cnt) {
    __shared__ unsigned long long sk[G];
    __shared__ unsigned int       sc[G];
    for (int i = threadIdx.x; i < G; i += BLK) { sk[i] = 0ull; sc[i] = 0u; }
    __syncthreads();

    const int vbase = blockIdx.x * CHUNK_VEC;

#define DO_ELEM(Y, GRP, IT)                                                        \
    {                                                                              \
        const unsigned int o = ord_f32(Y);                                         \
        const int          grp = (GRP);                                            \
        /* tear-proof prefilter: high word of sk[] is monotone non-decreasing */   \
        const unsigned int hi = ((volatile unsigned int*)&sk[grp])[1];             \
        if (o >= hi) {                                                             \
            unsigned long long key =                                               \
                ((unsigned long long)o << 32) | (unsigned int)(~(unsigned int)(IT)); \
            atomicMax(&sk[grp], key);                                              \
        }                                                                          \
        atomicAdd(&sc[grp], 1u);                                                   \
    }

    for (int t = threadIdx.x; t < CHUNK_VEC; t += BLK) {
        const int v = vbase + t;
        const float4 a  = lg[v];
        const float4 b  = zz[v];
        const int4   g4 = ix[v];
        const int item  = v * 4;
        DO_ELEM(a.x + b.x, g4.x, item + 0);
        DO_ELEM(a.y + b.y, g4.y, item + 1);
        DO_ELEM(a.z + b.z, g4.z, item + 2);
        DO_ELEM(a.w + b.w, g4.w, item + 3);
    }
#undef DO_ELEM

    __syncthreads();
    // transposed store -> pass2 reads coalesced
    for (int i = threadIdx.x; i < G; i += BLK) {
        ws_key[i * NBLK + blockIdx.x] = sk[i];
        ws_cnt[i * NBLK + blockIdx.x] = sc[i];
    }
}

// -----------------------------------------------------------------------------
// pass2: one block per group. Reduce chunk keys -> winner item P; rank =
// sum(counts of full chunks before P's chunk) + scan of P's chunk up to P.
// -----------------------------------------------------------------------------
__global__ __launch_bounds__(BLK) void pass2(const int* __restrict__ ix,
                                             const unsigned long long* __restrict__ ws_key,
                                             const unsigned int*       __restrict__ ws_cnt,
                                             int* __restrict__ out) {
    const int g   = blockIdx.x;
    const int tid = threadIdx.x;

    __shared__ unsigned long long rk[BLK];
    __shared__ unsigned int       rc[BLK];

    // 1) winner key for this group
    unsigned long long kmax = 0ull;
    for (int b = tid; b < NBLK; b += BLK) {
        const unsigned long long k = ws_key[(size_t)g * NBLK + b];
        if (k > kmax) kmax = k;
    }
    rk[tid] = kmax;
    __syncthreads();
    for (int s = BLK / 2; s > 0; s >>= 1) {
        if (tid < s) {
            if (rk[tid + s] > rk[tid]) rk[tid] = rk[tid + s];
        }
        __syncthreads();
    }
    kmax = rk[0];
    __syncthreads();

    if (kmax == 0ull) {   // empty group (cannot happen at these sizes) — rank 0
        if (tid == 0) out[g] = 0;
        return;
    }

    const unsigned int P  = ~(unsigned int)kmax;   // winning global item index
    const int          wb = (int)(P / CHUNK_ITEMS);

    // 2) full-chunk prefix counts
    unsigned int total = 0;
    for (int b = tid; b < wb; b += BLK) total += ws_cnt[(size_t)g * NBLK + b];

    // 3) partial scan of winner's chunk (L3-resident)
    for (unsigned int i = (unsigned int)wb * CHUNK_ITEMS + tid; i < P; i += BLK)
        total += (ix[i] == g) ? 1u : 0u;

    rc[tid] = total;
    __syncthreads();
    for (int s = BLK / 2; s > 0; s >>= 1) {
        if (tid < s) rc[tid] += rc[tid + s];
        __syncthreads();
    }
    if (tid == 0) out[g] = (int)rc[0];
}

// -----------------------------------------------------------------------------
extern "C" void kernel_launch(void* const* d_in, const int* in_sizes, int n_in,
                              void* d_out, int out_size, void* d_ws, size_t ws_size,
                              hipStream_t stream) {
    const float* logits = (const float*)d_in[0];
    const float* z      = (const float*)d_in[1];
    const int*   index  = (const int*)d_in[2];
    int*         out    = (int*)d_out;

    unsigned long long* ws_key = (unsigned long long*)d_ws;
    unsigned int*       ws_cnt = (unsigned int*)((char*)d_ws + (size_t)G * NBLK * sizeof(unsigned long long));

    pass1<<<NBLK, BLK, 0, stream>>>((const float4*)logits, (const float4*)z,
                                    (const int4*)index, ws_key, ws_cnt);
    pass2<<<G, BLK, 0, stream>>>(index, ws_key, ws_cnt, out);
}

// Round 3
// 126.135 us; speedup vs baseline: 1.0731x; 1.0731x over previous
//
#include <hip/hip_runtime.h>

// Segmented Gumbel-argmax sampler.
// out[g] = within-group rank (int32) of argmax_{i: index[i]==g} (logits[i]+z[i]),
//          first occurrence wins ties (min item idx at max y).
//
// N_ITEMS = 8388608, N_GROUPS = 512.  Output dtype: int32.
//
// pass1: 512 blocks x 1024 thr, each block owns a contiguous 16384-item chunk.
//        Streams logits+z+index once (96 MB -> BW floor ~15 us), reduces
//        per-(group,chunk) max-key + count in LDS, writes transposed to ws.
// pass2: 512 blocks (one per group) x 512 thr: reduce 512 chunk keys ->
//        winner item P; rank = prefix chunk counts + int4 scan of P's chunk.

#define G           512
#define NBLK        512        // pass1 blocks; each owns a contiguous chunk
#define BLK         1024       // pass1 threads (32 waves/CU at 2 blocks/CU)
#define BLK2        512        // pass2 threads
#define CHUNK_ITEMS 16384      // N_ITEMS / NBLK
#define CHUNK_VEC   4096       // CHUNK_ITEMS / 4 (float4 / int4 per chunk)

// monotone order-preserving float32 -> uint32 map (no NaNs in input)
__device__ __forceinline__ unsigned int ord_f32(float f) {
    unsigned int u = __float_as_uint(f);
    return (u & 0x80000000u) ? ~u : (u | 0x80000000u);
}

// -----------------------------------------------------------------------------
// pass1: per-chunk segmented max-key + per-chunk group counts.
// ws_key[g*NBLK + b] = max key of group g within chunk b (0 if absent)
// ws_cnt[g*NBLK + b] = #items of group g within chunk b
// -----------------------------------------------------------------------------
__global__ __launch_bounds__(BLK, 8) void pass1(const float4* __restrict__ lg,
                                                const float4* __restrict__ zz,
                                                const int4*   __restrict__ ix,
                                                unsigned long long* __restrict__ ws_key,
                                                unsigned int*       __restrict__ ws_cnt) {
    __shared__ unsigned long long sk[G];
    __shared__ unsigned int       sc[G];
    for (int i = threadIdx.x; i < G; i += BLK) { sk[i] = 0ull; sc[i] = 0u; }
    __syncthreads();

    const int vbase = blockIdx.x * CHUNK_VEC;

#define DO_ELEM(Y, GRP, IT)                                                        \
    {                                                                              \
        const unsigned int o = ord_f32(Y);                                         \
        const int          grp = (GRP);                                            \
        /* tear-proof prefilter: high word of sk[] is monotone non-decreasing */   \
        const unsigned int hi = ((volatile unsigned int*)&sk[grp])[1];             \
        if (o >= hi) {                                                             \
            unsigned long long key =                                               \
                ((unsigned long long)o << 32) | (unsigned int)(~(unsigned int)(IT)); \
            atomicMax(&sk[grp], key);                                              \
        }                                                                          \
        atomicAdd(&sc[grp], 1u);                                                   \
    }

    for (int t = threadIdx.x; t < CHUNK_VEC; t += BLK) {
        const int v = vbase + t;
        const float4 a  = lg[v];
        const float4 b  = zz[v];
        const int4   g4 = ix[v];
        const int item  = v * 4;
        DO_ELEM(a.x + b.x, g4.x, item + 0);
        DO_ELEM(a.y + b.y, g4.y, item + 1);
        DO_ELEM(a.z + b.z, g4.z, item + 2);
        DO_ELEM(a.w + b.w, g4.w, item + 3);
    }
#undef DO_ELEM

    __syncthreads();
    // transposed store -> pass2 reads coalesced
    for (int i = threadIdx.x; i < G; i += BLK) {
        ws_key[i * NBLK + blockIdx.x] = sk[i];
        ws_cnt[i * NBLK + blockIdx.x] = sc[i];
    }
}

// -----------------------------------------------------------------------------
// pass2: one block per group.
// -----------------------------------------------------------------------------
__global__ __launch_bounds__(BLK2) void pass2(const int* __restrict__ ix,
                                              const unsigned long long* __restrict__ ws_key,
                                              const unsigned int*       __restrict__ ws_cnt,
                                              int* __restrict__ out) {
    const int g   = blockIdx.x;
    const int tid = threadIdx.x;

    __shared__ unsigned long long rk[BLK2];
    __shared__ unsigned int       rc[BLK2];

    // 1) winner key for this group (one ws entry per thread, tree reduce)
    unsigned long long kmax = ws_key[(size_t)g * NBLK + tid];
    rk[tid] = kmax;
    __syncthreads();
    for (int s = BLK2 / 2; s > 0; s >>= 1) {
        if (tid < s) {
            if (rk[tid + s] > rk[tid]) rk[tid] = rk[tid + s];
        }
        __syncthreads();
    }
    kmax = rk[0];
    __syncthreads();

    if (kmax == 0ull) {   // empty group (cannot happen at these sizes)
        if (tid == 0) out[g] = 0;
        return;
    }

    const unsigned int P    = ~(unsigned int)kmax;   // winning global item index
    const int          wb   = (int)(P / CHUNK_ITEMS);
    const unsigned int base = (unsigned int)wb * CHUNK_ITEMS;

    // 2) full-chunk prefix counts
    unsigned int total = 0;
    for (int b = tid; b < wb; b += BLK2) total += ws_cnt[(size_t)g * NBLK + b];

    // 3) partial scan of winner's chunk [base, P) — int4 vectorized
    //    (base is 16384-aligned -> 64KB-aligned byte address)
    {
        const int4* ix4 = (const int4*)(ix + base);
        const int nvec  = (int)((P - base) >> 2);    // vec4 lanes fully below P
        for (int v = tid; v < nvec; v += BLK2) {
            const int4 q = ix4[v];
            total += (q.x == g) + (q.y == g) + (q.z == g) + (q.w == g);
        }
        if (tid == 0) {                               // <=3 tail items
            for (unsigned int i = base + ((unsigned int)nvec << 2); i < P; ++i)
                total += (ix[i] == g) ? 1u : 0u;
        }
    }

    rc[tid] = total;
    __syncthreads();
    for (int s = BLK2 / 2; s > 0; s >>= 1) {
        if (tid < s) rc[tid] += rc[tid + s];
        __syncthreads();
    }
    if (tid == 0) out[g] = (int)rc[0];
}

// -----------------------------------------------------------------------------
extern "C" void kernel_launch(void* const* d_in, const int* in_sizes, int n_in,
                              void* d_out, int out_size, void* d_ws, size_t ws_size,
                              hipStream_t stream) {
    const float* logits = (const float*)d_in[0];
    const float* z      = (const float*)d_in[1];
    const int*   index  = (const int*)d_in[2];
    int*         out    = (int*)d_out;

    unsigned long long* ws_key = (unsigned long long*)d_ws;
    unsigned int*       ws_cnt = (unsigned int*)((char*)d_ws + (size_t)G * NBLK * sizeof(unsigned long long));

    pass1<<<NBLK, BLK, 0, stream>>>((const float4*)logits, (const float4*)z,
                                    (const int4*)index, ws_key, ws_cnt);
    pass2<<<G, BLK2, 0, stream>>>(index, ws_key, ws_cnt, out);
}

// Round 5
// 122.558 us; speedup vs baseline: 1.1044x; 1.0292x over previous
//
#include <hip/hip_runtime.h>

// Segmented Gumbel-argmax sampler.
// out[g] = within-group rank (int32) of argmax_{i: index[i]==g} (logits[i]+z[i]),
//          first occurrence wins ties (min item idx at max y).
//
// N_ITEMS = 8388608, N_GROUPS = 512.  Output dtype: int32.
//
// pass1: 512 blocks x 1024 thr, each block owns a contiguous 16384-item chunk.
//        Streams logits+z+index once (96 MB -> BW floor ~15 us), reduces
//        per-(group,chunk) max-key + count in LDS, writes transposed to ws.
// pass2: 512 blocks (one per group) x 512 thr: shuffle-reduce 512 chunk keys
//        -> winner item P; rank = prefix chunk counts + int4 scan of P's chunk.

#define G           512
#define NBLK        512        // pass1 blocks; each owns a contiguous chunk
#define BLK         1024       // pass1 threads
#define BLK2        512        // pass2 threads
#define CHUNK_ITEMS 16384      // N_ITEMS / NBLK
#define CHUNK_VEC   4096       // CHUNK_ITEMS / 4 (float4 / int4 per chunk)
#define KITER       (CHUNK_VEC / BLK)   // 4 statically-unrolled steps

// monotone order-preserving float32 -> uint32 map (no NaNs in input)
__device__ __forceinline__ unsigned int ord_f32(float f) {
    unsigned int u = __float_as_uint(f);
    return (u & 0x80000000u) ? ~u : (u | 0x80000000u);
}

// -----------------------------------------------------------------------------
// pass1: per-chunk segmented max-key + per-chunk group counts.
// ws_key[g*NBLK + b] = max key of group g within chunk b (0 if absent)
// ws_cnt[g*NBLK + b] = #items of group g within chunk b
// -----------------------------------------------------------------------------
__global__ __launch_bounds__(BLK, 8) void pass1(const float4* __restrict__ lg,
                                                const float4* __restrict__ zz,
                                                const int4*   __restrict__ ix,
                                                unsigned long long* __restrict__ ws_key,
                                                unsigned int*       __restrict__ ws_cnt) {
    __shared__ unsigned long long sk[G];
    __shared__ unsigned int       sc[G];
    for (int i = threadIdx.x; i < G; i += BLK) { sk[i] = 0ull; sc[i] = 0u; }
    __syncthreads();

    const int vbase = blockIdx.x * CHUNK_VEC;

#define DO_ELEM(Y, GRP, IT)                                                        \
    {                                                                              \
        const unsigned int o = ord_f32(Y);                                         \
        const int          grp = (GRP);                                            \
        /* tear-proof prefilter: high word of sk[] is monotone non-decreasing */   \
        const unsigned int hi = ((volatile unsigned int*)&sk[grp])[1];             \
        if (o >= hi) {                                                             \
            unsigned long long key =                                               \
                ((unsigned long long)o << 32) | (unsigned int)(~(unsigned int)(IT)); \
            atomicMax(&sk[grp], key);                                              \
        }                                                                          \
        atomicAdd(&sc[grp], 1u);                                                   \
    }

#pragma unroll
    for (int k = 0; k < KITER; ++k) {
        const int v = vbase + threadIdx.x + k * BLK;
        const float4 a  = lg[v];
        const float4 b  = zz[v];
        const int4   g4 = ix[v];
        const int item  = v * 4;
        DO_ELEM(a.x + b.x, g4.x, item + 0);
        DO_ELEM(a.y + b.y, g4.y, item + 1);
        DO_ELEM(a.z + b.z, g4.z, item + 2);
        DO_ELEM(a.w + b.w, g4.w, item + 3);
    }
#undef DO_ELEM

    __syncthreads();
    // transposed store -> pass2 reads coalesced
    for (int i = threadIdx.x; i < G; i += BLK) {
        ws_key[i * NBLK + blockIdx.x] = sk[i];
        ws_cnt[i * NBLK + blockIdx.x] = sc[i];
    }
}

// -----------------------------------------------------------------------------
// pass2: one block per group.  Shuffle-based reductions (wave=64).
// -----------------------------------------------------------------------------
__global__ __launch_bounds__(BLK2) void pass2(const int* __restrict__ ix,
                                              const unsigned long long* __restrict__ ws_key,
                                              const unsigned int*       __restrict__ ws_cnt,
                                              int* __restrict__ out) {
    const int g    = blockIdx.x;
    const int tid  = threadIdx.x;
    const int lane = tid & 63;
    const int wave = tid >> 6;           // 8 waves

    __shared__ unsigned long long wk[8];
    __shared__ unsigned int       wc[8];

    // 1) winner key for this group (one ws entry per thread)
    unsigned long long kmax = ws_key[(size_t)g * NBLK + tid];
#pragma unroll
    for (int off = 32; off > 0; off >>= 1) {
        const unsigned long long o = __shfl_down(kmax, off, 64);
        if (o > kmax) kmax = o;
    }
    if (lane == 0) wk[wave] = kmax;
    __syncthreads();
    if (tid < 8) {
        kmax = wk[tid];
#pragma unroll
        for (int off = 4; off > 0; off >>= 1) {
            const unsigned long long o = __shfl_down(kmax, off, 64);
            if (o > kmax) kmax = o;
        }
        if (tid == 0) wk[0] = kmax;
    }
    __syncthreads();
    kmax = wk[0];

    const unsigned int P    = ~(unsigned int)kmax;   // winning global item index
    const int          wb   = (int)(P / CHUNK_ITEMS);
    const unsigned int base = (unsigned int)wb * CHUNK_ITEMS;

    // 2) full-chunk prefix counts (wb <= 511 -> <=1 entry per thread)
    unsigned int total = (tid < wb) ? ws_cnt[(size_t)g * NBLK + tid] : 0u;

    // 3) partial scan of winner's chunk [base, P) — int4 vectorized
    //    (base is 16384-aligned -> 64KB-aligned byte address)
    {
        const int4* ix4 = (const int4*)(ix + base);
        const int nvec  = (int)((P - base) >> 2);    // vec4 lanes fully below P
        for (int v = tid; v < nvec; v += BLK2) {
            const int4 q = ix4[v];
            total += (q.x == g) + (q.y == g) + (q.z == g) + (q.w == g);
        }
        if (tid == 0) {                               // <=3 tail items
            for (unsigned int i = base + ((unsigned int)nvec << 2); i < P; ++i)
                total += (ix[i] == g) ? 1u : 0u;
        }
    }

    // 4) sum-reduce total
#pragma unroll
    for (int off = 32; off > 0; off >>= 1)
        total += __shfl_down(total, off, 64);
    if (lane == 0) wc[wave] = total;
    __syncthreads();
    if (tid < 8) {
        total = wc[tid];
#pragma unroll
        for (int off = 4; off > 0; off >>= 1)
            total += __shfl_down(total, off, 64);
        if (tid == 0) out[g] = (int)total;
    }
}

// -----------------------------------------------------------------------------
extern "C" void kernel_launch(void* const* d_in, const int* in_sizes, int n_in,
                              void* d_out, int out_size, void* d_ws, size_t ws_size,
                              hipStream_t stream) {
    const float* logits = (const float*)d_in[0];
    const float* z      = (const float*)d_in[1];
    const int*   index  = (const int*)d_in[2];
    int*         out    = (int*)d_out;

    unsigned long long* ws_key = (unsigned long long*)d_ws;
    unsigned int*       ws_cnt = (unsigned int*)((char*)d_ws + (size_t)G * NBLK * sizeof(unsigned long long));

    pass1<<<NBLK, BLK, 0, stream>>>((const float4*)logits, (const float4*)z,
                                    (const int4*)index, ws_key, ws_cnt);
    pass2<<<G, BLK2, 0, stream>>>(index, ws_key, ws_cnt, out);
}